// Round 5
// baseline (905.849 us; speedup 1.0000x reference)
//
#include <hip/hip_runtime.h>
#include <hip/hip_bf16.h>
#include <math.h>

typedef __hip_bfloat16 bf16;
typedef __bf16 bf16x8 __attribute__((ext_vector_type(8)));
typedef float f32x4 __attribute__((ext_vector_type(4)));

#define BDIM 16
#define SDIM 2048
#define FDIM 1024
#define BS (BDIM * SDIM)  // 32768

__device__ __forceinline__ float bf2f(bf16 x) { return __bfloat162float(x); }
__device__ __forceinline__ bf16 f2bf(float x) { return __float2bfloat16(x); }

// ---------------------------------------------------------------------------
// MFMA GEMM. A-operand [M,K] row-major, f32 (AF32) or bf16; converted to bf16
// during LDS staging. B-operand [N,K] row-major bf16 (pre-transposed weights).
// K=1024, 128x128 tile, 16x16x32 bf16 MFMA.
// MODE 0: out[m,n] = relu(acc + bias[n]) -> bf16 or f32 per OUTF32
// MODE 1: logit[m] += sum_n tanh(acc[m,n] + t1[b,n]) * v[n]   (atomicAdd)
// ---------------------------------------------------------------------------
template <int MODE, bool AF32, bool OUTF32>
__global__ __launch_bounds__(256) void gemm_bt(
    const void* __restrict__ Agv, const bf16* __restrict__ Bg,
    const float* __restrict__ bias, void* __restrict__ outp,
    const float* __restrict__ t1, const float* __restrict__ vvec,
    float* __restrict__ logit) {
  constexpr int BK = 32, K = 1024;
  __shared__ __align__(16) bf16 As[128 * BK];
  __shared__ __align__(16) bf16 Bs[128 * BK];

  const int tid = threadIdx.x;
  const int lane = tid & 63;
  const int wave = tid >> 6;
  const int wm = (wave & 1) * 64;
  const int wn = (wave >> 1) * 64;
  const int tile_m = blockIdx.x * 128;
  const int tile_n = blockIdx.y * 128;
  const int ln = lane & 15;
  const int ko = (lane >> 4) * 8;

  f32x4 acc[4][4] = {};

  const int arow = tid >> 2;        // 0..63
  const int acol = (tid & 3) * 8;   // 0,8,16,24
  const size_t aoff = (size_t)(tile_m + arow) * K + acol;
  const size_t aoff2 = aoff + (size_t)64 * K;
  const bf16* gB = Bg + (size_t)(tile_n + arow) * K + acol;
  const size_t rstep = (size_t)64 * K;
  bf16* lA = &As[arow * BK + acol];
  bf16* lA2 = &As[(64 + arow) * BK + acol];
  bf16* lB = &Bs[arow * BK + acol];
  bf16* lB2 = &Bs[(64 + arow) * BK + acol];

  for (int k0 = 0; k0 < K; k0 += BK) {
    bf16x8 va, va2;
    if constexpr (AF32) {
      const float* pa = (const float*)Agv + aoff + k0;
      const float* pa2 = (const float*)Agv + aoff2 + k0;
      const float4 x0 = *(const float4*)pa, x1 = *(const float4*)(pa + 4);
      const float4 y0 = *(const float4*)pa2, y1 = *(const float4*)(pa2 + 4);
      va[0] = (__bf16)x0.x; va[1] = (__bf16)x0.y; va[2] = (__bf16)x0.z; va[3] = (__bf16)x0.w;
      va[4] = (__bf16)x1.x; va[5] = (__bf16)x1.y; va[6] = (__bf16)x1.z; va[7] = (__bf16)x1.w;
      va2[0] = (__bf16)y0.x; va2[1] = (__bf16)y0.y; va2[2] = (__bf16)y0.z; va2[3] = (__bf16)y0.w;
      va2[4] = (__bf16)y1.x; va2[5] = (__bf16)y1.y; va2[6] = (__bf16)y1.z; va2[7] = (__bf16)y1.w;
    } else {
      va = *(const bf16x8*)((const bf16*)Agv + aoff + k0);
      va2 = *(const bf16x8*)((const bf16*)Agv + aoff2 + k0);
    }
    const bf16x8 vb = *(const bf16x8*)(gB + k0);
    const bf16x8 vb2 = *(const bf16x8*)(gB + k0 + rstep);
    __syncthreads();  // prev iteration's fragment reads complete
    *(bf16x8*)lA = va;
    *(bf16x8*)lA2 = va2;
    *(bf16x8*)lB = vb;
    *(bf16x8*)lB2 = vb2;
    __syncthreads();
    bf16x8 af[4], bfr[4];
#pragma unroll
    for (int i = 0; i < 4; i++)
      af[i] = *(const bf16x8*)&As[(wm + i * 16 + ln) * BK + ko];
#pragma unroll
    for (int j = 0; j < 4; j++)
      bfr[j] = *(const bf16x8*)&Bs[(wn + j * 16 + ln) * BK + ko];
#pragma unroll
    for (int i = 0; i < 4; i++)
#pragma unroll
      for (int j = 0; j < 4; j++)
        acc[i][j] =
            __builtin_amdgcn_mfma_f32_16x16x32_bf16(af[i], bfr[j], acc[i][j], 0, 0, 0);
  }

  if (MODE == 0) {
#pragma unroll
    for (int i = 0; i < 4; i++) {
#pragma unroll
      for (int j = 0; j < 4; j++) {
        const int colg = tile_n + wn + j * 16 + ln;
        const float bv = bias[colg];
#pragma unroll
        for (int r = 0; r < 4; r++) {
          const int rowg = tile_m + wm + i * 16 + ((lane >> 4) << 2) + r;
          const float val = fmaxf(acc[i][j][r] + bv, 0.f);
          if constexpr (OUTF32)
            ((float*)outp)[(size_t)rowg * FDIM + colg] = val;
          else
            ((bf16*)outp)[(size_t)rowg * FDIM + colg] = f2bf(val);
        }
      }
    }
  } else {
    const int b = tile_m >> 11;  // /SDIM
    float tcol[4], vcol[4];
#pragma unroll
    for (int j = 0; j < 4; j++) {
      const int colg = tile_n + wn + j * 16 + ln;
      tcol[j] = t1[b * FDIM + colg];
      vcol[j] = vvec[colg];
    }
#pragma unroll
    for (int i = 0; i < 4; i++) {
#pragma unroll
      for (int r = 0; r < 4; r++) {
        float s = 0.f;
#pragma unroll
        for (int j = 0; j < 4; j++) s += tanhf(acc[i][j][r] + tcol[j]) * vcol[j];
        s += __shfl_xor(s, 1);
        s += __shfl_xor(s, 2);
        s += __shfl_xor(s, 4);
        s += __shfl_xor(s, 8);
        if (ln == 0) {
          const int rowg = tile_m + wm + i * 16 + ((lane >> 4) << 2) + r;
          atomicAdd(&logit[rowg], s);
        }
      }
    }
  }
}

// dst[n*K + k] = bf16(src[k*N + n]); src f32 [K,N]
__global__ void transpose_cvt_k(const float* __restrict__ src, bf16* __restrict__ dst,
                                int K, int N) {
  __shared__ bf16 t[32][33];
  const int n0 = blockIdx.x * 32, k0 = blockIdx.y * 32;
  const int tx = threadIdx.x, ty = threadIdx.y;
  for (int i = 0; i < 32; i += 8)
    t[ty + i][tx] = f2bf(src[(size_t)(k0 + ty + i) * N + n0 + tx]);
  __syncthreads();
  for (int i = 0; i < 32; i += 8)
    dst[(size_t)(n0 + ty + i) * K + k0 + tx] = t[tx][ty + i];
}

__global__ void zerof_k(float* __restrict__ a, int n) {
  const int i = blockIdx.x * 256 + threadIdx.x;
  if (i < n) a[i] = 0.f;
}

__global__ void copyf_k(const float* __restrict__ in, float* __restrict__ out, int n) {
  const int i = blockIdx.x * 256 + threadIdx.x;
  if (i < n) out[i] = in[i];
}

// outf[b,f] += sum_{s in chunk} M[b*S+s, f] * w[b,s]   (atomic, outf pre-zeroed)
__global__ void colreduce_k(const bf16* __restrict__ M, const float* __restrict__ w,
                            float* __restrict__ outf) {
  const int b = blockIdx.y;
  const int f = blockIdx.x * 256 + threadIdx.x;
  const int s0 = blockIdx.z * 128;
  const bf16* col = M + ((size_t)b * SDIM + s0) * FDIM + f;
  const float* wb = w + b * SDIM + s0;
  float acc = 0.f;
#pragma unroll 8
  for (int s = 0; s < 128; ++s) acc += bf2f(col[(size_t)s * FDIM]) * wb[s];
  atomicAdd(&outf[b * FDIM + f], acc);
}

// out[b,n] = sum_f invec[b,f] * w1[f,n] + bias[n]   (all f32)
__global__ void smallgemm_k(const float* __restrict__ invec, const float* __restrict__ w1,
                            const float* __restrict__ bias, float* __restrict__ out) {
  const int b = blockIdx.y;
  const int n = blockIdx.x * 256 + threadIdx.x;
  const float* q = invec + b * FDIM;
  float acc = 0.f;
#pragma unroll 8
  for (int f = 0; f < FDIM; ++f) acc += q[f] * w1[(size_t)f * FDIM + n];
  out[b * FDIM + n] = acc + bias[n];
}

__global__ void softmax_k(const float* __restrict__ logit, const float* __restrict__ mask,
                          float* __restrict__ alpha) {
  const int b = blockIdx.x, tid = threadIdx.x;
  __shared__ float red[4];
  float v[8];
  float lmax = -1e30f;
#pragma unroll
  for (int k = 0; k < 8; ++k) {
    const int s = tid + k * 256;
    const float m = (1.f - mask[b * SDIM + s]) * -10000.f;
    v[k] = logit[b * SDIM + s] + m;
    lmax = fmaxf(lmax, v[k]);
  }
  for (int m = 1; m < 64; m <<= 1) lmax = fmaxf(lmax, __shfl_xor(lmax, m));
  if ((tid & 63) == 0) red[tid >> 6] = lmax;
  __syncthreads();
  lmax = fmaxf(fmaxf(red[0], red[1]), fmaxf(red[2], red[3]));
  __syncthreads();
  float lsum = 0.f;
#pragma unroll
  for (int k = 0; k < 8; ++k) {
    v[k] = expf(v[k] - lmax);
    lsum += v[k];
  }
  for (int m = 1; m < 64; m <<= 1) lsum += __shfl_xor(lsum, m);
  if ((tid & 63) == 0) red[tid >> 6] = lsum;
  __syncthreads();
  const float inv = 1.f / (red[0] + red[1] + red[2] + red[3]);
#pragma unroll
  for (int k = 0; k < 8; ++k) alpha[b * SDIM + tid + k * 256] = v[k] * inv;
}

__global__ void sparsemax_k(const float* __restrict__ Ll, const float* __restrict__ mask,
                            const float* __restrict__ w1s, const float* __restrict__ w2s,
                            const float* __restrict__ w3s, const int* __restrict__ layer_i,
                            float* __restrict__ Lout) {
  const int b = blockIdx.x, tid = threadIdx.x;
  __shared__ float red[4];
  const float a1 = w1s[0], a2 = w2s[0], a3 = w3s[0];
  const int li = layer_i[0];
  const float x = (li == 0) ? (a3 * a3 - a2 * a2 - a1 * a1)
                            : ((li == 1) ? (a3 * a3 - a2 * a2) : (a3 * a3));
  const float sig = 1.f / (1.f + expf(-x));
  float z[8];
  float lmax = -1e30f;
#pragma unroll
  for (int k = 0; k < 8; ++k) {
    const int s = tid + k * 256;
    const float m = (1.f - mask[b * SDIM + s]) * -10000.f;
    z[k] = Ll[b * SDIM + s] * sig + m;
    lmax = fmaxf(lmax, z[k]);
  }
  for (int m = 1; m < 64; m <<= 1) lmax = fmaxf(lmax, __shfl_xor(lmax, m));
  if ((tid & 63) == 0) red[tid >> 6] = lmax;
  __syncthreads();
  const float zmax = fmaxf(fmaxf(red[0], red[1]), fmaxf(red[2], red[3]));
  __syncthreads();
  float lo = zmax - 1.f, hi = zmax;
  for (int it = 0; it < 40; ++it) {
    const float tau = 0.5f * (lo + hi);
    float ssum = 0.f;
#pragma unroll
    for (int k = 0; k < 8; ++k) ssum += fmaxf(z[k] - tau, 0.f);
    for (int m = 1; m < 64; m <<= 1) ssum += __shfl_xor(ssum, m);
    if ((tid & 63) == 0) red[tid >> 6] = ssum;
    __syncthreads();
    const float tot = red[0] + red[1] + red[2] + red[3];
    __syncthreads();
    if (tot > 1.f) lo = tau; else hi = tau;
  }
  const float tau = 0.5f * (lo + hi);
#pragma unroll
  for (int k = 0; k < 8; ++k)
    Lout[b * SDIM + tid + k * 256] = fmaxf(z[k] - tau, 0.f);
}

extern "C" void kernel_launch(void* const* d_in, const int* in_sizes, int n_in,
                              void* d_out, int out_size, void* d_ws, size_t ws_size,
                              hipStream_t stream) {
  // Inputs AND outputs are float32 (reference dtype); layer_i int32.
  const float* mask = (const float*)d_in[0];
  const float* xlnet = (const float*)d_in[1];
  const float* iw = (const float*)d_in[2];
  const float* W_C = (const float*)d_in[3];
  const float* b_C = (const float*)d_in[4];
  const float* W_A = (const float*)d_in[5];
  const float* b_A = (const float*)d_in[6];
  const float* w1 = (const float*)d_in[7];
  const float* w2 = (const float*)d_in[8];
  const float* attn_bias = (const float*)d_in[9];
  const float* v = (const float*)d_in[10];
  const float* w_1 = (const float*)d_in[11];
  const float* w_2 = (const float*)d_in[12];
  const float* w_3 = (const float*)d_in[13];
  const int* layer_i = (const int*)d_in[14];

  float* out = (float*)d_out;
  float* h_out = out;                 // 16384 f32
  float* L_out = out + 16384;         // 32768 f32
  float* A_out = out + 49152;         // 33554432 f32 (134 MB)
  bf16* Cbuf = (bf16*)A_out;          // C (bf16, 67 MB) staged in A's slot,
                                      // fully consumed before A overwrites it.

  // ws: 3 bf16 transposed weights (6 MB) + f32 smalls (~655 KB).
  char* ws = (char*)d_ws;
  bf16* WT_C = (bf16*)(ws);                      // 2 MB
  bf16* WT_A = (bf16*)(ws + 2097152);            // 2 MB
  bf16* w2T = (bf16*)(ws + 4194304);             // 2 MB
  float* qbuf = (float*)(ws + 6291456);          // 64 KB
  float* t1q = (float*)(ws + 6356992);           // 64 KB
  float* t1h = (float*)(ws + 6422528);           // 64 KB
  float* hbuf = (float*)(ws + 6488064);          // 64 KB
  float* a_logit = (float*)(ws + 6553600);       // 128 KB
  float* alpha = (float*)(ws + 6684672);         // 128 KB
  float* L_logit = (float*)(ws + 6815744);       // 128 KB -> end 6946816

  const dim3 tb(32, 8);
  transpose_cvt_k<<<dim3(32, 32), tb, 0, stream>>>(W_C, WT_C, 1024, 1024);
  transpose_cvt_k<<<dim3(32, 32), tb, 0, stream>>>(W_A, WT_A, 1024, 1024);
  transpose_cvt_k<<<dim3(32, 32), tb, 0, stream>>>(w2, w2T, 1024, 1024);
  // zero qbuf..L_logit contiguous region (163840 floats)
  zerof_k<<<640, 256, 0, stream>>>(qbuf, 163840);

  // C = relu(X@W_C + b_C) -> Cbuf (bf16, in A's output slot)
  gemm_bt<0, true, false><<<dim3(BS / 128, 8), 256, 0, stream>>>(
      xlnet, WT_C, b_C, Cbuf, nullptr, nullptr, nullptr);
  // q[b,f] = sum_s C * iw
  colreduce_k<<<dim3(4, BDIM, 16), 256, 0, stream>>>(Cbuf, iw, qbuf);
  // t1q = q @ w1 + attn_bias
  smallgemm_k<<<dim3(4, BDIM), 256, 0, stream>>>(qbuf, w1, attn_bias, t1q);
  // a_logit[m] = sum_n tanh((C@w2)[m,n] + t1q[b,n]) * v[n]
  gemm_bt<1, false, false><<<dim3(BS / 128, 8), 256, 0, stream>>>(
      Cbuf, w2T, nullptr, nullptr, t1q, v, a_logit);
  softmax_k<<<BDIM, 256, 0, stream>>>(a_logit, mask, alpha);
  // h[b,f] = sum_s C * alpha
  colreduce_k<<<dim3(4, BDIM, 16), 256, 0, stream>>>(Cbuf, alpha, hbuf);
  copyf_k<<<64, 256, 0, stream>>>(hbuf, h_out, BDIM * FDIM);
  smallgemm_k<<<dim3(4, BDIM), 256, 0, stream>>>(hbuf, w1, attn_bias, t1h);
  // A = relu(X@W_A + b_A) -> A_out f32 (overwrites Cbuf; C fully consumed)
  gemm_bt<0, true, true><<<dim3(BS / 128, 8), 256, 0, stream>>>(
      xlnet, WT_A, b_A, A_out, nullptr, nullptr, nullptr);
  // L_logit[m] = sum_n tanh((A@w2)[m,n] + t1h[b,n]) * v[n]
  gemm_bt<1, true, false><<<dim3(BS / 128, 8), 256, 0, stream>>>(
      A_out, w2T, nullptr, nullptr, t1h, v, L_logit);
  sparsemax_k<<<BDIM, 256, 0, stream>>>(L_logit, mask, w_1, w_2, w_3, layer_i, L_out);
}